// Round 7
// baseline (134.921 us; speedup 1.0000x reference)
//
#include <hip/hip_runtime.h>
#include <hip/hip_bf16.h>
#include <math.h>

#define B_  2
#define S_  2048
#define H_  16
#define D_  64
#define SST 40   // score-strip stride (shorts): 80 B rows, 16B-aligned

typedef __attribute__((ext_vector_type(8))) short bf16x8_t;
typedef __attribute__((ext_vector_type(4))) float f32x4_t;

__device__ __forceinline__ unsigned short f2bf(float f) {
    __hip_bfloat16 h = __float2bfloat16(f);
    return __builtin_bit_cast(unsigned short, h);
}

// async global->LDS, 16B per lane; LDS dest = wave-uniform base + lane*16
__device__ __forceinline__ void async16(const unsigned short* g, unsigned short* l) {
    __builtin_amdgcn_global_load_lds(
        (const __attribute__((address_space(1))) unsigned int*)g,
        (__attribute__((address_space(3))) unsigned int*)l, 16, 0, 0);
}

#define WAITV2 asm volatile("s_waitcnt vmcnt(2)" ::: "memory")
#define WAITV0 asm volatile("s_waitcnt vmcnt(0)" ::: "memory")
#define BAR    asm volatile("s_barrier" ::: "memory")

// ---------------- kernel 1: fused prep (unchanged; correctness-proven) ----------
__global__ __launch_bounds__(256) void prep_kernel(const float* __restrict__ Q,
                                                   const float* __restrict__ K,
                                                   const float* __restrict__ V,
                                                   unsigned short* __restrict__ qb,
                                                   unsigned short* __restrict__ kb,
                                                   unsigned short* __restrict__ vt) {
    __shared__ float tile[64 * 65];
    int t   = threadIdx.x;
    int bh  = blockIdx.x >> 4;
    int scn = blockIdx.x & 15;
    int b = bh >> 4, hh = bh & 15;
    int s0 = scn * 128;

    float lnv   = -3.4657359027997265f + (float)hh * (-0.18483924814931874f);
    float gamma = 1.0f - expf(lnv);
    float l2g   = log2f(gamma);

#pragma unroll
    for (int it = 0; it < 16; ++it) {
        int idx = it * 256 + t;
        int i  = idx & 31;
        int sl = idx >> 5;
        int s  = s0 + sl;
        float pos = (float)s;

        float bsc  = (2.0f * (float)i + 25.6f) / 89.6f;
        float xsc  = exp2f(log2f(bsc) * pos * (1.0f / 512.0f));
        float invf = exp2f(-(float)i * (13.287712379549449f / 32.0f));
        float ang  = pos * invf;
        float kq = rintf(ang * 0.15915494309189535f);
        float r  = fmaf(kq, -6.2831853071795865f, ang);
        float sn = sinf(r), cs = cosf(r);

        float gs  = exp2f(pos * l2g);
        float gsi = exp2f(-pos * l2g);
        float rxs = 1.0f / xsc;

        float cq = cs * xsc * gs,  sq = sn * xsc * gs;
        float ck = cs * rxs * gsi, sk = sn * rxs * gsi;

        long inIdx = ((long)(b * S_ + s)) * 1024 + hh * 64 + 2 * i;
        float2 xq = *(const float2*)(Q + inIdx);
        float2 xk = *(const float2*)(K + inIdx);
        float q0 = xq.x * cq - xq.y * sq, q1 = xq.y * cq + xq.x * sq;
        float k0 = xk.x * ck - xk.y * sk, k1 = xk.y * ck + xk.x * sk;

        long outIdx = ((long)(bh * S_ + s)) * 64 + 2 * i;
        *(unsigned int*)(qb + outIdx) = (unsigned)f2bf(q0) | ((unsigned)f2bf(q1) << 16);
        *(unsigned int*)(kb + outIdx) = (unsigned)f2bf(k0) | ((unsigned)f2bf(k1) << 16);
    }

#pragma unroll
    for (int half = 0; half < 2; ++half) {
        __syncthreads();
        int sb = s0 + half * 64;
#pragma unroll
        for (int it = 0; it < 4; ++it) {
            int f  = it * 256 + t;
            int sl = f >> 4;
            int d4 = f & 15;
            float4 v = *(const float4*)(V + ((long)(b * S_ + sb + sl)) * 1024 + hh * 64 + d4 * 4);
            tile[sl * 65 + d4 * 4 + 0] = v.x;
            tile[sl * 65 + d4 * 4 + 1] = v.y;
            tile[sl * 65 + d4 * 4 + 2] = v.z;
            tile[sl * 65 + d4 * 4 + 3] = v.w;
        }
        __syncthreads();
        int d = t >> 2, c = t & 3;
        unsigned int pk[8];
#pragma unroll
        for (int jj = 0; jj < 8; ++jj) {
            float f0 = tile[(c * 16 + 2 * jj + 0) * 65 + d];
            float f1 = tile[(c * 16 + 2 * jj + 1) * 65 + d];
            pk[jj] = (unsigned int)f2bf(f0) | ((unsigned int)f2bf(f1) << 16);
        }
        unsigned short* outp = vt + ((long)(bh * 64 + d)) * S_ + sb + c * 16;
        ((uint4*)outp)[0] = make_uint4(pk[0], pk[1], pk[2], pk[3]);
        ((uint4*)outp)[1] = make_uint4(pk[4], pk[5], pk[6], pk[7]);
    }
}

// ---------------- kernel 2: retention, kv-half wave-split, TRIPLE-buffered ----------------
// 512 blocks x 512 threads. Wave (qw,p): qw = 32 q-rows, p = kv-half of every tile.
// 3 K/V LDS buffers, ONE barrier per tile: WAIT(own i) -> BAR -> stage(i+2) -> compute(i).
// BAR at step i proves compute(i-1) done by all -> buffer (i+2)%3 == (i-1)%3 is free.
// Buffers rotate as uniform (SGPR) pointers — never runtime-indexed reg arrays (R3 lesson).
__global__ __launch_bounds__(512, 4) void retention_kernel(const unsigned short* __restrict__ qb,
                                                           const unsigned short* __restrict__ kb,
                                                           const unsigned short* __restrict__ vt,
                                                           float* __restrict__ out) {
    __shared__ __align__(16) unsigned short KV[24576];        // 3 x [K|V], 4096 shorts each
    __shared__ __align__(16) unsigned short Ss[8][32 * SST];  // wave-private score strips

    int t = threadIdx.x;
    int w = t >> 6, lane = t & 63, quad = lane >> 4, l16 = lane & 15;
    int qw = w & 3;          // q-subtile (32 rows)
    int p  = w >> 2;         // kv-half (0: cols 0..31, 1: cols 32..63)

    // longest-first dispatch
    int i  = blockIdx.x;
    int g  = 15 - (i >> 5);
    int bh = i & 31;
    int b = bh >> 4, hh = bh & 15;

    int q0w  = g * 128 + qw * 32;
    int dkt  = 2 * g + (qw >> 1);     // wave's diagonal KV tile
    int odd  = qw & 1;                // row offset within diagonal tile = odd*32
    int kvend = 2 * g + 2;            // tiles this block walks (>= 2, even)

    const unsigned short* qB = qb + ((long)bh * S_ + q0w) * 64;
    const unsigned short* kB = kb + (long)bh * S_ * 64;
    const unsigned short* vB = vt + (long)bh * 64 * S_;

    bf16x8_t aQ[2][2];
#pragma unroll
    for (int m = 0; m < 2; ++m)
#pragma unroll
        for (int kk = 0; kk < 2; ++kk)
            aQ[m][kk] = *(const bf16x8_t*)(qB + (m * 16 + l16) * 64 + kk * 32 + quad * 8);

    f32x4_t acc[2][4];   // partial O over this wave's kv-half
#pragma unroll
    for (int m = 0; m < 2; ++m)
#pragma unroll
        for (int nd = 0; nd < 4; ++nd) acc[m][nd] = (f32x4_t){0.f, 0.f, 0.f, 0.f};

    // stage one K+V tile into the given buffer: 8 waves x (1 K + 1 V DMA), 1 KB each.
    // 16B block (row, c) stored at slot c ^ (row&7)  [bank swizzle]
    auto stage = [&](unsigned short* Kd, unsigned short* Vd, int kt) {
        const unsigned short* kSrc = kB + kt * 4096;
        const unsigned short* vSrc = vB + kt * 64;
        int row = w * 8 + (lane >> 3);
        int c   = (lane & 7) ^ (row & 7);
        async16(kSrc + row * 64 + c * 8, Kd + w * 512);
        async16(vSrc + (long)row * S_ + c * 8, Vd + w * 512);
    };

    // one wave's slice of one tile: 32 q-rows x its 32 kv-cols
    auto computeHalf = [&](const unsigned short* Kt, const unsigned short* Vt, bool diag) {
        f32x4_t sc[2][2];
#pragma unroll
        for (int m = 0; m < 2; ++m)
#pragma unroll
            for (int ntl = 0; ntl < 2; ++ntl) sc[m][ntl] = (f32x4_t){0.f, 0.f, 0.f, 0.f};

#pragma unroll
        for (int kk = 0; kk < 2; ++kk)
#pragma unroll
            for (int ntl = 0; ntl < 2; ++ntl) {
                int krow = p * 32 + ntl * 16 + l16;
                bf16x8_t bk = *(const bf16x8_t*)&Kt[krow * 64 +
                                                   (((kk * 4 + quad) ^ (krow & 7)) * 8)];
                sc[0][ntl] = __builtin_amdgcn_mfma_f32_16x16x32_bf16(aQ[0][kk], bk, sc[0][ntl], 0, 0, 0);
                sc[1][ntl] = __builtin_amdgcn_mfma_f32_16x16x32_bf16(aQ[1][kk], bk, sc[1][ntl], 0, 0, 0);
            }

        unsigned short* ssw = Ss[w];
        if (!diag) {
#pragma unroll
            for (int m = 0; m < 2; ++m)
#pragma unroll
                for (int ntl = 0; ntl < 2; ++ntl)
#pragma unroll
                    for (int r = 0; r < 4; ++r)
                        ssw[(m * 16 + quad * 4 + r) * SST + ntl * 16 + l16] = f2bf(sc[m][ntl][r]);
        } else {   // p == odd triangular case: keep iff (quad*4+r) + (m-ntl)*16 >= l16
#pragma unroll
            for (int m = 0; m < 2; ++m)
#pragma unroll
                for (int ntl = 0; ntl < 2; ++ntl) {
                    int dlt = (m - ntl) * 16;
#pragma unroll
                    for (int r = 0; r < 4; ++r) {
                        int rr = quad * 4 + r;
                        float v = ((rr + dlt) >= l16) ? sc[m][ntl][r] : 0.0f;
                        ssw[(m * 16 + rr) * SST + ntl * 16 + l16] = f2bf(v);
                    }
                }
        }

        // PV: A = wave's 16x32 score strips, B = V^T chunks (kv-half p)
        bf16x8_t aS0 = *(const bf16x8_t*)&ssw[(0 * 16 + l16) * SST + quad * 8];
        bf16x8_t aS1 = *(const bf16x8_t*)&ssw[(1 * 16 + l16) * SST + quad * 8];
#pragma unroll
        for (int nd = 0; nd < 4; ++nd) {
            int vrow = nd * 16 + l16;
            bf16x8_t bv = *(const bf16x8_t*)&Vt[vrow * 64 +
                                               (((p * 4 + quad) ^ (vrow & 7)) * 8)];
            acc[0][nd] = __builtin_amdgcn_mfma_f32_16x16x32_bf16(aS0, bv, acc[0][nd], 0, 0, 0);
            acc[1][nd] = __builtin_amdgcn_mfma_f32_16x16x32_bf16(aS1, bv, acc[1][nd], 0, 0, 0);
        }
    };

    // rotating buffer pointers (uniform; SGPR-held)
    unsigned short *Ka = KV,         *Va = KV + 4096;
    unsigned short *Kb2 = KV + 8192, *Vb2 = KV + 12288;
    unsigned short *Kc = KV + 16384, *Vc = KV + 20480;

    stage(Ka, Va, 0);
    stage(Kb2, Vb2, 1);
    for (int kt = 0; kt < kvend; ++kt) {
        if (kt < kvend - 1) { WAITV2; } else { WAITV0; }
        BAR;                              // all waves: tile-kt DMAs done AND compute(kt-1) done
        if (kt + 2 < kvend) stage(Kc, Vc, kt + 2);
        if (kt < dkt || (kt == dkt && p <= odd)) computeHalf(Ka, Va, kt == dkt && p == odd);
        // rotate: a <- b <- c <- a
        unsigned short* tk = Ka; Ka = Kb2; Kb2 = Kc; Kc = tk;
        unsigned short* tv = Va; Va = Vb2; Vb2 = Vc; Vc = tv;
    }
    BAR;                                  // compute(kvend-1) done by all before overlay reuse

    // ---- reduce the two kv-half partials (overlay scratch on dead K/V buffers) ----
    float* red = (float*)KV;          // 8192 floats; 2048 per qw
    if (p == 1) {
#pragma unroll
        for (int m = 0; m < 2; ++m)
#pragma unroll
            for (int nd = 0; nd < 4; ++nd)
#pragma unroll
                for (int r = 0; r < 4; ++r)
                    red[qw * 2048 + (m * 16 + quad * 4 + r) * 64 + nd * 16 + l16] = acc[m][nd][r];
    }
    BAR;
    if (p == 0) {
#pragma unroll
        for (int m = 0; m < 2; ++m)
#pragma unroll
            for (int nd = 0; nd < 4; ++nd)
#pragma unroll
                for (int r = 0; r < 4; ++r) {
                    int row = q0w + m * 16 + quad * 4 + r;
                    float v = acc[m][nd][r] +
                              red[qw * 2048 + (m * 16 + quad * 4 + r) * 64 + nd * 16 + l16];
                    out[((long)(b * S_ + row)) * 1024 + hh * 64 + nd * 16 + l16] = v;
                }
    }
}

extern "C" void kernel_launch(void* const* d_in, const int* in_sizes, int n_in,
                              void* d_out, int out_size, void* d_ws, size_t ws_size,
                              hipStream_t stream) {
    const float* Q = (const float*)d_in[0];
    const float* K = (const float*)d_in[1];
    const float* V = (const float*)d_in[2];
    float* out = (float*)d_out;

    const size_t perBuf = (size_t)B_ * H_ * S_ * D_;
    unsigned short* qb = (unsigned short*)d_ws;
    unsigned short* kb = qb + perBuf;
    unsigned short* vt = kb + perBuf;

    hipLaunchKernelGGL(prep_kernel, dim3(512), dim3(256), 0, stream, Q, K, V, qb, kb, vt);
    hipLaunchKernelGGL(retention_kernel, dim3(512), dim3(512), 0, stream, qb, kb, vt, out);
}

// Round 9
// 134.356 us; speedup vs baseline: 1.0042x; 1.0042x over previous
//
#include <hip/hip_runtime.h>
#include <hip/hip_bf16.h>
#include <math.h>

#define B_  2
#define S_  2048
#define H_  16
#define D_  64
#define NB  4194304   // elems per (B,H,S,64) buffer
#define SST 72        // score-strip stride (shorts): 64 cols + 8 pad, 16B-aligned rows

typedef __attribute__((ext_vector_type(8))) short bf16x8_t;
typedef __attribute__((ext_vector_type(4))) float f32x4_t;

__device__ __forceinline__ unsigned short f2bf(float f) {
    __hip_bfloat16 h = __float2bfloat16(f);
    return __builtin_bit_cast(unsigned short, h);
}

// ---------------- kernel 1: prep ----------------
// Chunk-LOCAL decay folding (numerical range O(1..1e4), no 1e33 bf16 states):
//   q'' = xpos_up(q) * gamma^(s%64)   -> qb (B,H,S,64)
//   k'' = xpos_down(k) * gamma^-(s%64) -> kb (row-major) AND kt (B,H,64,S)
//   v -> vt (B,H,64,S)
__global__ __launch_bounds__(256) void prep_kernel(const float* __restrict__ Q,
                                                   const float* __restrict__ K,
                                                   const float* __restrict__ V,
                                                   unsigned short* __restrict__ qb,
                                                   unsigned short* __restrict__ kb,
                                                   unsigned short* __restrict__ kt,
                                                   unsigned short* __restrict__ vt) {
    __shared__ float tile[64 * 65];                       // phase B (fp32 V)
    unsigned short* tile2 = (unsigned short*)tile;        // overlay, [64][68] shorts
    int t   = threadIdx.x;
    int bh  = blockIdx.x >> 4;
    int scn = blockIdx.x & 15;
    int b = bh >> 4, hh = bh & 15;
    int s0 = scn * 128;

    float lnv   = -3.4657359027997265f + (float)hh * (-0.18483924814931874f);
    float gamma = 1.0f - expf(lnv);
    float l2g   = log2f(gamma);

    // ---- phase A: xpos + local decay for Q,K; K'' also staged in LDS for transpose ----
#pragma unroll
    for (int half = 0; half < 2; ++half) {
        int sb0 = s0 + half * 64;
#pragma unroll
        for (int it = 0; it < 8; ++it) {
            int idx = it * 256 + t;          // 2048 = 64 rows x 32 pairs
            int i  = idx & 31;
            int sl = idx >> 5;
            int s  = sb0 + sl;
            float pos = (float)s;
            float lpos = (float)(s & 63);    // chunk-local position

            float bsc  = (2.0f * (float)i + 25.6f) / 89.6f;
            float xsc  = exp2f(log2f(bsc) * pos * (1.0f / 512.0f));
            float invf = exp2f(-(float)i * (13.287712379549449f / 32.0f));
            float ang  = pos * invf;
            float kq = rintf(ang * 0.15915494309189535f);
            float r  = fmaf(kq, -6.2831853071795865f, ang);
            float sn = sinf(r), cs = cosf(r);

            float gs  = exp2f(lpos * l2g);     // gamma^(s%64)   <= 1
            float gsi = exp2f(-lpos * l2g);    // gamma^-(s%64)  <= ~7.4
            float rxs = 1.0f / xsc;

            float cq = cs * xsc * gs,  sq = sn * xsc * gs;
            float ck = cs * rxs * gsi, sk = sn * rxs * gsi;

            long inIdx = ((long)(b * S_ + s)) * 1024 + hh * 64 + 2 * i;
            float2 xq = *(const float2*)(Q + inIdx);
            float2 xk = *(const float2*)(K + inIdx);
            float q0 = xq.x * cq - xq.y * sq, q1 = xq.y * cq + xq.x * sq;
            float k0 = xk.x * ck - xk.y * sk, k1 = xk.y * ck + xk.x * sk;

            unsigned short k0b = f2bf(k0), k1b = f2bf(k1);
            long outIdx = ((long)(bh * S_ + s)) * 64 + 2 * i;
            *(unsigned int*)(qb + outIdx) = (unsigned)f2bf(q0) | ((unsigned)f2bf(q1) << 16);
            *(unsigned int*)(kb + outIdx) = (unsigned)k0b | ((unsigned)k1b << 16);
            tile2[sl * 68 + 2 * i]     = k0b;
            tile2[sl * 68 + 2 * i + 1] = k1b;
        }
        __syncthreads();
        {   // transpose K'' out of LDS: kt row d, m-contiguous
            int d = t >> 2, cc = t & 3;
            unsigned int pk[8];
#pragma unroll
            for (int jj = 0; jj < 8; ++jj) {
                unsigned short a  = tile2[(cc * 16 + 2 * jj + 0) * 68 + d];
                unsigned short bb = tile2[(cc * 16 + 2 * jj + 1) * 68 + d];
                pk[jj] = (unsigned int)a | ((unsigned int)bb << 16);
            }
            unsigned short* op = kt + ((long)(bh * 64 + d)) * S_ + sb0 + cc * 16;
            ((uint4*)op)[0] = make_uint4(pk[0], pk[1], pk[2], pk[3]);
            ((uint4*)op)[1] = make_uint4(pk[4], pk[5], pk[6], pk[7]);
        }
        __syncthreads();
    }

    // ---- phase B: V transpose (fp32 via LDS), two 64-row halves ----
#pragma unroll
    for (int half = 0; half < 2; ++half) {
        int sb = s0 + half * 64;
#pragma unroll
        for (int it = 0; it < 4; ++it) {
            int f  = it * 256 + t;
            int sl = f >> 4;
            int d4 = f & 15;
            float4 v = *(const float4*)(V + ((long)(b * S_ + sb + sl)) * 1024 + hh * 64 + d4 * 4);
            tile[sl * 65 + d4 * 4 + 0] = v.x;
            tile[sl * 65 + d4 * 4 + 1] = v.y;
            tile[sl * 65 + d4 * 4 + 2] = v.z;
            tile[sl * 65 + d4 * 4 + 3] = v.w;
        }
        __syncthreads();
        int d = t >> 2, c = t & 3;
        unsigned int pk[8];
#pragma unroll
        for (int jj = 0; jj < 8; ++jj) {
            float f0 = tile[(c * 16 + 2 * jj + 0) * 65 + d];
            float f1 = tile[(c * 16 + 2 * jj + 1) * 65 + d];
            pk[jj] = (unsigned int)f2bf(f0) | ((unsigned int)f2bf(f1) << 16);
        }
        unsigned short* outp = vt + ((long)(bh * 64 + d)) * S_ + sb + c * 16;
        ((uint4*)outp)[0] = make_uint4(pk[0], pk[1], pk[2], pk[3]);
        ((uint4*)outp)[1] = make_uint4(pk[4], pk[5], pk[6], pk[7]);
        __syncthreads();
    }
}

// ---------------- kernel 2: per-chunk outer products ----------------
// Ut[bh][c][d2][d1] = sum_{mu in chunk} v[mu][d2] * k''[mu][d1]   (fp32)
__global__ __launch_bounds__(256) void chunk_u_kernel(const unsigned short* __restrict__ kt,
                                                      const unsigned short* __restrict__ vt,
                                                      float* __restrict__ ut) {
    int c  = blockIdx.x & 31;
    int bh = blockIdx.x >> 5;
    int t = threadIdx.x;
    int w = t >> 6, lane = t & 63, quad = lane >> 4, l16 = lane & 15;

    const unsigned short* ktB = kt + (long)bh * 64 * S_ + c * 64;
    const unsigned short* vtB = vt + (long)bh * 64 * S_ + c * 64;

    f32x4_t u[4];
#pragma unroll
    for (int nt = 0; nt < 4; ++nt) u[nt] = (f32x4_t){0.f, 0.f, 0.f, 0.f};

#pragma unroll
    for (int kk = 0; kk < 2; ++kk) {
        bf16x8_t av = *(const bf16x8_t*)(vtB + (long)(w * 16 + l16) * S_ + kk * 32 + quad * 8);
#pragma unroll
        for (int nt = 0; nt < 4; ++nt) {
            bf16x8_t bk = *(const bf16x8_t*)(ktB + (long)(nt * 16 + l16) * S_ + kk * 32 + quad * 8);
            u[nt] = __builtin_amdgcn_mfma_f32_16x16x32_bf16(av, bk, u[nt], 0, 0, 0);
        }
    }

    float* uo = ut + ((long)bh * 32 + c) * 4096;
#pragma unroll
    for (int nt = 0; nt < 4; ++nt)
#pragma unroll
        for (int r = 0; r < 4; ++r)
            uo[(w * 16 + quad * 4 + r) * 64 + nt * 16 + l16] = u[nt][r];
}

// ---------------- kernel 3: decayed prefix-scan of the states ----------------
// S_0 = 0;  S_{c+1} = gamma^64 * (S_c + U_c);  Sb[bh][c] = bf16(S_c).
// 131072 independent element-recurrences, fp32.
__global__ __launch_bounds__(256) void scan_kernel(const float* __restrict__ ut,
                                                   unsigned short* __restrict__ sb) {
    int bh = blockIdx.x >> 4;
    int hh = bh & 15;
    float lnv   = -3.4657359027997265f + (float)hh * (-0.18483924814931874f);
    float gamma = 1.0f - expf(lnv);
    float g64   = exp2f(64.0f * log2f(gamma));   // gamma^64

    int e = (blockIdx.x & 15) * 256 + threadIdx.x;     // 0..4095
    long base = (long)bh * 131072 + e;
    float st = 0.0f;
#pragma unroll
    for (int c = 0; c < 32; ++c) {
        sb[base + c * 4096] = f2bf(st);
        st = g64 * (st + ut[base + c * 4096]);
    }
}

// ---------------- kernel 4: main — intra(diag) + q''.State, barrier-free ----------------
// 1024 uniform blocks (bh x chunk), 4 waves; wave w owns q-rows [c*64+w*16, +16).
__global__ __launch_bounds__(256) void main_kernel(const unsigned short* __restrict__ qb,
                                                   const unsigned short* __restrict__ kb,
                                                   const unsigned short* __restrict__ vt,
                                                   const unsigned short* __restrict__ sb,
                                                   float* __restrict__ out) {
    __shared__ __align__(16) unsigned short Ss[4][16 * SST];   // wave-private 16x64 strips

    int c  = blockIdx.x & 31;
    int bh = blockIdx.x >> 5;
    int t = threadIdx.x;
    int w = t >> 6, lane = t & 63, quad = lane >> 4, l16 = lane & 15;
    int b = bh >> 4, hh = bh & 15;

    const unsigned short* qB  = qb + ((long)bh * S_ + c * 64 + w * 16) * 64;
    const unsigned short* kB  = kb + ((long)bh * S_ + c * 64) * 64;
    const unsigned short* vtB = vt + (long)bh * 64 * S_ + c * 64;
    const unsigned short* sB  = sb + ((long)bh * 32 + c) * 4096;

    bf16x8_t aQ[2];
#pragma unroll
    for (int kk = 0; kk < 2; ++kk)
        aQ[kk] = *(const bf16x8_t*)(qB + l16 * 64 + kk * 32 + quad * 8);

    f32x4_t acc[4];
#pragma unroll
    for (int nd = 0; nd < 4; ++nd) acc[nd] = (f32x4_t){0.f, 0.f, 0.f, 0.f};

    // ---- inter: O += Q'' . State  (B-frag rows = d2, d1-contiguous) ----
#pragma unroll
    for (int kk = 0; kk < 2; ++kk)
#pragma unroll
        for (int nd = 0; nd < 4; ++nd) {
            bf16x8_t bs = *(const bf16x8_t*)(sB + (nd * 16 + l16) * 64 + kk * 32 + quad * 8);
            acc[nd] = __builtin_amdgcn_mfma_f32_16x16x32_bf16(aQ[kk], bs, acc[nd], 0, 0, 0);
        }

    // ---- intra: masked diagonal-chunk scores ----
    f32x4_t sc[4];
#pragma unroll
    for (int nt = 0; nt < 4; ++nt) sc[nt] = (f32x4_t){0.f, 0.f, 0.f, 0.f};
#pragma unroll
    for (int kk = 0; kk < 2; ++kk)
#pragma unroll
        for (int nt = 0; nt < 4; ++nt)
            if (nt <= w) {   // nt > w: strictly above diagonal, all-zero
                bf16x8_t bk = *(const bf16x8_t*)(kB + (nt * 16 + l16) * 64 + kk * 32 + quad * 8);
                sc[nt] = __builtin_amdgcn_mfma_f32_16x16x32_bf16(aQ[kk], bk, sc[nt], 0, 0, 0);
            }

    unsigned short* ssw = Ss[w];
#pragma unroll
    for (int nt = 0; nt < 4; ++nt)
#pragma unroll
        for (int r = 0; r < 4; ++r) {
            float v;
            if (nt < w)       v = sc[nt][r];
            else if (nt == w) v = ((quad * 4 + r) >= l16) ? sc[nt][r] : 0.0f;
            else              v = 0.0f;
            ssw[(quad * 4 + r) * SST + nt * 16 + l16] = f2bf(v);
        }
    // wave-private LDS round-trip (no barrier; R2-proven pattern)

#pragma unroll
    for (int kp2 = 0; kp2 < 2; ++kp2) {
        bf16x8_t aS = *(const bf16x8_t*)&ssw[l16 * SST + kp2 * 32 + quad * 8];
#pragma unroll
        for (int nd = 0; nd < 4; ++nd) {
            bf16x8_t bv = *(const bf16x8_t*)(vtB + (long)(nd * 16 + l16) * S_ + kp2 * 32 + quad * 8);
            acc[nd] = __builtin_amdgcn_mfma_f32_16x16x32_bf16(aS, bv, acc[nd], 0, 0, 0);
        }
    }

    // ---- epilogue: C layout row=quad*4+r, col=l16 ----
#pragma unroll
    for (int nd = 0; nd < 4; ++nd)
#pragma unroll
        for (int r = 0; r < 4; ++r) {
            int row = c * 64 + w * 16 + quad * 4 + r;
            out[((long)(b * S_ + row)) * 1024 + hh * 64 + nd * 16 + l16] = acc[nd][r];
        }
}

extern "C" void kernel_launch(void* const* d_in, const int* in_sizes, int n_in,
                              void* d_out, int out_size, void* d_ws, size_t ws_size,
                              hipStream_t stream) {
    const float* Q = (const float*)d_in[0];
    const float* K = (const float*)d_in[1];
    const float* V = (const float*)d_in[2];
    float* out = (float*)d_out;

    unsigned short* qb = (unsigned short*)d_ws;
    unsigned short* kb = qb + NB;
    unsigned short* vt = kb + NB;
    unsigned short* kt = vt + NB;
    float*          ut = (float*)(kt + NB);      // 16 MB fp32
    unsigned short* sb = (unsigned short*)(ut + NB);

    hipLaunchKernelGGL(prep_kernel,    dim3(512),  dim3(256), 0, stream, Q, K, V, qb, kb, kt, vt);
    hipLaunchKernelGGL(chunk_u_kernel, dim3(1024), dim3(256), 0, stream, kt, vt, ut);
    hipLaunchKernelGGL(scan_kernel,    dim3(512),  dim3(256), 0, stream, ut, sb);
    hipLaunchKernelGGL(main_kernel,    dim3(1024), dim3(256), 0, stream, qb, kb, vt, sb, out);
}